// Round 3
// baseline (167.795 us; speedup 1.0000x reference)
//
#include <hip/hip_runtime.h>
#include <hip/hip_bf16.h>
#include <cstdint>

#define BB 64
#define NN 512
#define MM 1024
#define DD 128

typedef __bf16 bf16x8 __attribute__((ext_vector_type(8)));
typedef float f32x4 __attribute__((ext_vector_type(4)));

static __device__ __forceinline__ float bf2f(unsigned short u) {
    union { unsigned int i; float f; } v; v.i = ((unsigned int)u) << 16; return v.f;
}
static __device__ __forceinline__ unsigned short f2bf(float f) {
    union { float f; unsigned int i; } v; v.f = f;
    unsigned int x = v.i;
    x += 0x7FFFu + ((x >> 16) & 1u);   // RNE
    return (unsigned short)(x >> 16);
}

// ---------------- Kernel 1: Y = relu(X @ W^T + b) -----------------------------
// X fp32 (rows,128), W fp32 (128,128) [e][d], bias fp32, Y bf16 (rows,128).
// 64 rows per block; fp32->bf16 conversion during LDS staging; bf16 MFMA.
__global__ __launch_bounds__(256) void proj_relu_kernel(
    const float* __restrict__ X,
    const float* __restrict__ W,
    const float* __restrict__ bias,
    unsigned short* __restrict__ Y)
{
    __shared__ unsigned short Xs[64 * 136];
    __shared__ unsigned short Ws[128 * 136];
    const int t = threadIdx.x;
    const int lane = t & 63;
    const int wave = t >> 6;
    const int n16 = lane & 15, q = lane >> 4;
    const long row0 = (long)blockIdx.x * 64;

    // stage X tile (64x128 fp32 -> bf16) and W (128x128 fp32 -> bf16)
    {
        const float4* Xg = (const float4*)(X + row0 * DD);
        #pragma unroll
        for (int i = 0; i < 8; ++i) {
            int idx = i * 256 + t;            // float4 index, 2048 total
            float4 v = Xg[idx];
            int off = idx * 4;
            ushort4 u = { f2bf(v.x), f2bf(v.y), f2bf(v.z), f2bf(v.w) };
            *(ushort4*)&Xs[(off >> 7) * 136 + (off & 127)] = u;
        }
        const float4* Wg = (const float4*)W;
        #pragma unroll
        for (int i = 0; i < 16; ++i) {
            int idx = i * 256 + t;            // 4096 total
            float4 v = Wg[idx];
            int off = idx * 4;
            ushort4 u = { f2bf(v.x), f2bf(v.y), f2bf(v.z), f2bf(v.w) };
            *(ushort4*)&Ws[(off >> 7) * 136 + (off & 127)] = u;
        }
    }
    __syncthreads();

    f32x4 acc[8];
    #pragma unroll
    for (int j = 0; j < 8; ++j) acc[j] = {0.f, 0.f, 0.f, 0.f};

    const unsigned short* arow = &Xs[(wave * 16 + n16) * 136 + q * 8];
    #pragma unroll
    for (int kk = 0; kk < 4; ++kk) {
        bf16x8 a = *(const bf16x8*)(arow + kk * 32);
        #pragma unroll
        for (int j = 0; j < 8; ++j) {
            bf16x8 b = *(const bf16x8*)&Ws[(j * 16 + n16) * 136 + q * 8 + kk * 32];
            acc[j] = __builtin_amdgcn_mfma_f32_16x16x32_bf16(a, b, acc[j], 0, 0, 0);
        }
    }

    #pragma unroll
    for (int j = 0; j < 8; ++j) {
        int e = j * 16 + n16;
        float bv = bias[e];
        #pragma unroll
        for (int r = 0; r < 4; ++r) {
            int row = wave * 16 + q * 4 + r;
            float v = acc[j][r] + bv;
            v = v > 0.f ? v : 0.f;
            Y[(row0 + row) * DD + e] = f2bf(v);
        }
    }
}

// ---------------- Kernel 2: fused bilinear attention + mean reduction ---------
// Each block: one (b, 64-row n-tile). 4 waves; wave owns 16 n-rows.
__global__ __launch_bounds__(256) void attn_kernel(
    const unsigned short* __restrict__ Uc,   // (B*N,128) bf16
    const unsigned short* __restrict__ Vp,   // (B*M,128) bf16
    const float* __restrict__ qv,            // (128) fp32
    float* __restrict__ out_acc)             // (B,128) fp32, pre-zeroed
{
    __shared__ unsigned short Qs[64 * 136];
    __shared__ unsigned short Vs[64 * 136];
    __shared__ unsigned short VTs[128 * 72];
    __shared__ unsigned short Ps[4][16 * 72];

    const int t = threadIdx.x;
    const int lane = t & 63;
    const int wave = t >> 6;
    const int n16 = lane & 15, q = lane >> 4;
    const int b = blockIdx.x >> 3;
    const int nt = blockIdx.x & 7;
    const long ucbase = ((long)b * NN + nt * 64) * DD;
    const long vpbase = (long)b * MM * DD;

    // stage Q tile (Uc rows) 64x128 bf16
    {
        const uint4* Qg = (const uint4*)(Uc + ucbase);
        #pragma unroll
        for (int i = 0; i < 4; ++i) {
            int off = i * 2048 + t * 8;
            uint4 v = Qg[i * 256 + t];
            *(uint4*)&Qs[(off >> 7) * 136 + (off & 127)] = v;
        }
    }

    f32x4 O[8];
    #pragma unroll
    for (int j = 0; j < 8; ++j) O[j] = {0.f, 0.f, 0.f, 0.f};
    float m_i[4], l_i[4];
    #pragma unroll
    for (int r = 0; r < 4; ++r) { m_i[r] = -1e30f; l_i[r] = 0.f; }

    for (int mt = 0; mt < 16; ++mt) {
        __syncthreads();   // protect Vs/VTs reuse (also covers Qs first use)
        // stage Vp tile 64x128 into Vs (row-major) and VTs (transposed)
        {
            const int mr = t & 63;
            const int d0 = (t >> 6) * 32;
            const uint4* vg = (const uint4*)(Vp + vpbase + (long)(mt * 64 + mr) * DD + d0);
            #pragma unroll
            for (int i = 0; i < 4; ++i) {
                uint4 v = vg[i];
                *(uint4*)&Vs[mr * 136 + d0 + i * 8] = v;
                const unsigned short* pv = (const unsigned short*)&v;
                #pragma unroll
                for (int jj = 0; jj < 8; ++jj)
                    VTs[(d0 + i * 8 + jj) * 72 + mr] = pv[jj];
            }
        }
        __syncthreads();

        // S = Q * Vp^T  (16 n-rows x 64 m-cols per wave)
        f32x4 S[4];
        #pragma unroll
        for (int j = 0; j < 4; ++j) S[j] = {0.f, 0.f, 0.f, 0.f};
        #pragma unroll
        for (int kk = 0; kk < 4; ++kk) {
            bf16x8 a = *(const bf16x8*)&Qs[(wave * 16 + n16) * 136 + q * 8 + kk * 32];
            #pragma unroll
            for (int j = 0; j < 4; ++j) {
                bf16x8 bb = *(const bf16x8*)&Vs[(j * 16 + n16) * 136 + q * 8 + kk * 32];
                S[j] = __builtin_amdgcn_mfma_f32_16x16x32_bf16(a, bb, S[j], 0, 0, 0);
            }
        }

        // online softmax, per C-layout row r (global row = wave*16 + q*4 + r)
        #pragma unroll
        for (int r = 0; r < 4; ++r) {
            float mx = fmaxf(fmaxf(S[0][r], S[1][r]), fmaxf(S[2][r], S[3][r]));
            mx = fmaxf(mx, __shfl_xor(mx, 1));
            mx = fmaxf(mx, __shfl_xor(mx, 2));
            mx = fmaxf(mx, __shfl_xor(mx, 4));
            mx = fmaxf(mx, __shfl_xor(mx, 8));
            float mnew = fmaxf(m_i[r], mx);
            float alpha = __expf(m_i[r] - mnew);
            float p0 = __expf(S[0][r] - mnew);
            float p1 = __expf(S[1][r] - mnew);
            float p2 = __expf(S[2][r] - mnew);
            float p3 = __expf(S[3][r] - mnew);
            float sum = p0 + p1 + p2 + p3;
            sum += __shfl_xor(sum, 1);
            sum += __shfl_xor(sum, 2);
            sum += __shfl_xor(sum, 4);
            sum += __shfl_xor(sum, 8);
            l_i[r] = l_i[r] * alpha + sum;
            m_i[r] = mnew;
            #pragma unroll
            for (int j = 0; j < 8; ++j) O[j][r] *= alpha;
            const int prow = (q * 4 + r) * 72;
            Ps[wave][prow +  0 + n16] = f2bf(p0);
            Ps[wave][prow + 16 + n16] = f2bf(p1);
            Ps[wave][prow + 32 + n16] = f2bf(p2);
            Ps[wave][prow + 48 + n16] = f2bf(p3);
        }

        // O += P * Vp  (B-operand = VTs rows = Vp columns)
        #pragma unroll
        for (int kk = 0; kk < 2; ++kk) {
            bf16x8 a = *(const bf16x8*)&Ps[wave][n16 * 72 + q * 8 + kk * 32];
            #pragma unroll
            for (int j = 0; j < 8; ++j) {
                bf16x8 bb = *(const bf16x8*)&VTs[(j * 16 + n16) * 72 + q * 8 + kk * 32];
                O[j] = __builtin_amdgcn_mfma_f32_16x16x32_bf16(a, bb, O[j], 0, 0, 0);
            }
        }
    }

    // epilogue: out[b][d] += (1/N) * sum_n (Uc[n][d] + O[n][d]/l[n]) * q[d]
    const float invN = 1.0f / (float)NN;
    float res[8];
    #pragma unroll
    for (int j = 0; j < 8; ++j) {
        int d = j * 16 + n16;
        float s = 0.f;
        #pragma unroll
        for (int r = 0; r < 4; ++r) {
            float ctx = O[j][r] / l_i[r];
            float uc = bf2f(Qs[(wave * 16 + q * 4 + r) * 136 + d]);
            s += ctx + uc;
        }
        s += __shfl_xor(s, 16);
        s += __shfl_xor(s, 32);
        res[j] = s;
    }
    if (q == 0) {
        #pragma unroll
        for (int j = 0; j < 8; ++j) {
            int d = j * 16 + n16;
            atomicAdd(&out_acc[b * DD + d], res[j] * qv[d] * invN);
        }
    }
}

// ---------------- Kernel 3: fp32 accumulator -> fp32 output -------------------
__global__ __launch_bounds__(256) void finalize_kernel(
    const float* __restrict__ acc, float* __restrict__ out)
{
    int i = blockIdx.x * 256 + threadIdx.x;
    out[i] = acc[i];
}

extern "C" void kernel_launch(void* const* d_in, const int* in_sizes, int n_in,
                              void* d_out, int out_size, void* d_ws, size_t ws_size,
                              hipStream_t stream) {
    const float* h_c = (const float*)d_in[0];
    const float* h_p = (const float*)d_in[1];
    const float* U_w = (const float*)d_in[2];
    const float* U_b = (const float*)d_in[3];
    const float* V_w = (const float*)d_in[4];
    const float* V_b = (const float*)d_in[5];
    const float* qv  = (const float*)d_in[6];
    float* out = (float*)d_out;

    unsigned short* Uc = (unsigned short*)d_ws;                       // B*N*D bf16
    unsigned short* Vp = Uc + (size_t)BB * NN * DD;                   // B*M*D bf16
    float* acc = (float*)(Vp + (size_t)BB * MM * DD);                 // B*D fp32

    hipMemsetAsync(acc, 0, (size_t)BB * DD * sizeof(float), stream);
    proj_relu_kernel<<<BB * NN / 64, 256, 0, stream>>>(h_c, U_w, U_b, Uc);
    proj_relu_kernel<<<BB * MM / 64, 256, 0, stream>>>(h_p, V_w, V_b, Vp);
    attn_kernel<<<BB * 8, 256, 0, stream>>>(Uc, Vp, qv, acc);
    finalize_kernel<<<BB * DD / 256, 256, 0, stream>>>(acc, out);
}